// Round 2
// baseline (70.767 us; speedup 1.0000x reference)
//
#include <hip/hip_runtime.h>

#define IN_C 64
#define OUT_C 64
#define HW 32

// LDS carve-up (floats):
//   xs : 64 ch * 4 padded rows * 36 cols   = 9216
//   ws : 576 ckk * 4 och                   = 2304
//   red: 8 cs * 64 sp * 5 (padded)         = 2560
#define XS_ELEMS (64 * 4 * 36)
#define WS_ELEMS (576 * 4)
#define RED_ELEMS (8 * 64 * 5)

// grid 512 = b(2) * og(16) * tile(16); block 512 = cs(8) * sp(64)
// tile = 2 output rows; og = 4 consecutive out-channels; cs = 8-channel slice.
__global__ __launch_bounds__(512, 4) void norm_conv_fused(
    const float* __restrict__ x, const float* __restrict__ w,
    const float* __restrict__ bias, float* __restrict__ out) {
    __shared__ float smem[XS_ELEMS + WS_ELEMS + RED_ELEMS];
    float* xs = smem;                    // [c][r(4)][36]
    float* wsm = smem + XS_ELEMS;        // [ckk][4 och]
    float* red = wsm + WS_ELEMS;         // [cs][sp][5]

    int bid = blockIdx.x;
    int tile = bid & 15;
    int og = (bid >> 4) & 15;
    int b = bid >> 8;
    int tid = threadIdx.x;

    // ---- stage weights: w[o][ckk] -> wsm[ckk*4 + och], och in [0,4) ----
    for (int i = tid; i < 576 * 4; i += 512) {
        int och = i / 576;
        int ckk = i - och * 576;
        wsm[ckk * 4 + och] = w[(og * 4 + och) * 576 + ckk];
    }

    // ---- stage x tile with zero padding: rows tile*2-1 .. tile*2+2, cols -1..32 ----
    for (int i = tid; i < 64 * 4 * 34; i += 512) {
        int c = i / 136;            // 136 = 4*34
        int rem = i - c * 136;
        int r = rem / 34;
        int pc = rem - r * 34;      // padded col 0..33
        int gr = tile * 2 - 1 + r;  // global row
        int gc = pc - 1;            // global col
        float v = 0.0f;
        if (gr >= 0 && gr < HW && gc >= 0 && gc < HW)
            v = x[((b * IN_C + c) * HW + gr) * HW + gc];
        xs[(c * 4 + r) * 36 + pc] = v;
    }
    __syncthreads();

    // ---- main accumulation: each thread = 1 spatial pos x 4 och, 8 channels ----
    int sp = tid & 63;
    int cs = tid >> 6;          // wave-uniform (waves are 64 threads)
    int row = sp >> 5, col = sp & 31;

    float s0 = 0.f, s1 = 0.f, s2 = 0.f, s3 = 0.f;

    for (int c = 0; c < 8; ++c) {
        int c4 = cs * 8 + c;
        const float* xr = xs + (c4 * 4 + row) * 36 + col;
        const float* wr = wsm + c4 * 9 * 4;
#pragma unroll
        for (int kh = 0; kh < 3; ++kh) {
#pragma unroll
            for (int kw = 0; kw < 3; ++kw) {
                float xv = xr[kh * 36 + kw];
                float4 wv = *(const float4*)(wr + (kh * 3 + kw) * 4);
                float d0 = xv - wv.x;
                float d1 = xv - wv.y;
                float d2 = xv - wv.z;
                float d3 = xv - wv.w;
                d0 *= d0; d0 *= d0; s0 = fmaf(d0, d0, s0);
                d1 *= d1; d1 *= d1; s1 = fmaf(d1, d1, s1);
                d2 *= d2; d2 *= d2; s2 = fmaf(d2, d2, s2);
                d3 *= d3; d3 *= d3; s3 = fmaf(d3, d3, s3);
            }
        }
    }

    // ---- reduce the 8 c-slices (stride-5 rows -> conflict-free) ----
    float* rrow = red + (cs * 64 + sp) * 5;
    rrow[0] = s0; rrow[1] = s1; rrow[2] = s2; rrow[3] = s3;
    __syncthreads();

    if (tid < 256) {
        int sp2 = tid & 63;
        int oi = tid >> 6;
        float sum = 0.f;
#pragma unroll
        for (int k = 0; k < 8; ++k)
            sum += red[(k * 64 + sp2) * 5 + oi];
        float y = exp2f(0.125f * log2f(sum));  // sum^(1/8)
        int o = og * 4 + oi;
        int oh = tile * 2 + (sp2 >> 5);
        int ow = sp2 & 31;
        out[((b * OUT_C + o) * HW + oh) * HW + ow] = y + bias[o];
    }
}

extern "C" void kernel_launch(void* const* d_in, const int* in_sizes, int n_in,
                              void* d_out, int out_size, void* d_ws, size_t ws_size,
                              hipStream_t stream) {
    const float* x = (const float*)d_in[0];      // [2,64,32,32]
    const float* w = (const float*)d_in[1];      // [64,64,3,3]
    const float* bias = (const float*)d_in[2];   // [64]
    float* out = (float*)d_out;                  // [2,64,32,32]
    norm_conv_fused<<<512, 512, 0, stream>>>(x, w, bias, out);
}